// Round 1
// baseline (2333.726 us; speedup 1.0000x reference)
//
#include <hip/hip_runtime.h>
#include <cstddef>

// VOneBlock: gabor(5x5,s2) -> simple/complex nonlin -> divisive norm (dense 256ch 3x3) -> divide
// Round 1: fp32 correctness-first baseline.
// ws layout (floats): [0, 33554432) y_nhwc [32][64][64][256]; [33554432, +589824) gt [ky][kx][ci][co]

#define NSC 128

__global__ __launch_bounds__(256) void prep_gt(const float* __restrict__ g,
                                               float* __restrict__ gt) {
    int o = blockIdx.x * 256 + threadIdx.x;   // 589824 total = 9*256*256
    int co  = o & 255;
    int ci  = (o >> 8) & 255;
    int kxy = o >> 16;                         // 0..8 = ky*3+kx
    gt[o] = g[(co * 256 + ci) * 9 + kxy];
}

__global__ __launch_bounds__(256) void gabor(const float* __restrict__ x,
                                             const float* __restrict__ wq0,
                                             const float* __restrict__ wq1,
                                             float* __restrict__ y) {
    __shared__ float xbuf[5][132];            // rows ihb..ihb+4, cols iw+2 (pad 2 each side)
    int oh = blockIdx.x, b = blockIdx.y, c = threadIdx.x;
    for (int i = c; i < 5 * 132; i += 256) (&xbuf[0][0])[i] = 0.f;
    __syncthreads();
    int ihb = oh * 2 - 2;
    for (int i = c; i < 5 * 128; i += 256) {
        int r = i >> 7, col = i & 127;
        int ih = ihb + r;
        if ((unsigned)ih < 128u)
            xbuf[r][col + 2] = x[((size_t)b * 128 + ih) * 128 + col];
    }
    float w0[25], w1[25];
#pragma unroll
    for (int i = 0; i < 25; ++i) w0[i] = wq0[c * 25 + i];
#pragma unroll
    for (int i = 0; i < 25; ++i) w1[i] = wq1[c * 25 + i];
    __syncthreads();
    float* yrow = y + ((size_t)(b * 64 + oh) * 64) * 256 + c;
    for (int ow = 0; ow < 64; ++ow) {
        float q0 = 0.f, q1 = 0.f;
        int cb = ow * 2;
#pragma unroll
        for (int ky = 0; ky < 5; ++ky)
#pragma unroll
            for (int kx = 0; kx < 5; ++kx) {
                float xv = xbuf[ky][cb + kx];
                q0 = fmaf(w0[ky * 5 + kx], xv, q0);
                q1 = fmaf(w1[ky * 5 + kx], xv, q1);
            }
        float v = (c < NSC) ? fmaxf(q0, 0.f)
                            : sqrtf(fmaf(q0, q0, q1 * q1)) * 0.70710678118654752f;
        yrow[(size_t)ow * 256] = 25.f * v;    // relu(25*v) == 25*v since v>=0
    }
}

// block: 64 co x 64 w for one (b,h). 256 thr: tx=tid&15 -> w=tx*4.., ty=tid>>4 -> co=co0+ty*4..
__global__ __launch_bounds__(256) void dn(const float* __restrict__ y,
                                          const float* __restrict__ gt,
                                          float* __restrict__ out) {
    __shared__ float rbuf[32][68];            // [ci][1+w], col0 & col65 are zero pad; 68 for 16B align
    __shared__ float gbuf[3 * 32 * 64];       // [kx][ci][co']
    int cot = blockIdx.x, h = blockIdx.y, b = blockIdx.z;
    int tid = threadIdx.x;
    int tx = tid & 15, ty = tid >> 4;
    int co0 = cot * 64;
    float acc[4][4];
#pragma unroll
    for (int i = 0; i < 4; ++i)
#pragma unroll
        for (int j = 0; j < 4; ++j) acc[i][j] = 0.f;

    for (int ky = 0; ky < 3; ++ky) {
        int hh = h + ky - 1;
        bool vrow = (unsigned)hh < 64u;
        for (int ci0 = 0; ci0 < 256; ci0 += 32) {
            __syncthreads();                   // protect prior-iter reads
            if (tid < 32) { rbuf[tid][0] = 0.f; rbuf[tid][65] = 0.f; }
            {
                int ci = tid & 31, wb = tid >> 5;  // wb 0..7
                if (vrow) {
                    const float* src = y + ((size_t)(b * 64 + hh) * 64) * 256 + ci0 + ci;
#pragma unroll
                    for (int p = 0; p < 8; ++p)
                        rbuf[ci][1 + wb + p * 8] = src[(size_t)(wb + p * 8) * 256];
                } else {
#pragma unroll
                    for (int p = 0; p < 8; ++p) rbuf[ci][1 + wb + p * 8] = 0.f;
                }
            }
#pragma unroll
            for (int p = 0; p < 6; ++p) {      // stage G: 3kx*32ci*64co floats as float4
                int lin = p * 256 + tid;
                int co4 = lin & 15, ci = (lin >> 4) & 31, kx = lin >> 9;
                float4 v = *(const float4*)&gt[((size_t)(ky * 3 + kx) * 256 + ci0 + ci) * 256 + co0 + co4 * 4];
                *(float4*)&gbuf[(kx * 32 + ci) * 64 + co4 * 4] = v;
            }
            __syncthreads();
#pragma unroll 4
            for (int ci = 0; ci < 32; ++ci) {
                float4 r0 = *(const float4*)&rbuf[ci][tx * 4];
                float2 r1 = *(const float2*)&rbuf[ci][tx * 4 + 4];
                float rv[6] = {r0.x, r0.y, r0.z, r0.w, r1.x, r1.y};
#pragma unroll
                for (int kx = 0; kx < 3; ++kx) {
                    float4 gv = *(const float4*)&gbuf[(kx * 32 + ci) * 64 + ty * 4];
#pragma unroll
                    for (int j = 0; j < 4; ++j) {
                        acc[0][j] = fmaf(gv.x, rv[kx + j], acc[0][j]);
                        acc[1][j] = fmaf(gv.y, rv[kx + j], acc[1][j]);
                        acc[2][j] = fmaf(gv.z, rv[kx + j], acc[2][j]);
                        acc[3][j] = fmaf(gv.w, rv[kx + j], acc[3][j]);
                    }
                }
            }
        }
    }
    // epilogue: out = y / under, write NCHW
    const float* yc = y + ((size_t)(b * 64 + h) * 64) * 256 + co0 + ty * 4;
    float num[4][4];                           // [j][i]
#pragma unroll
    for (int j = 0; j < 4; ++j) {
        float4 v = *(const float4*)&yc[(size_t)(tx * 4 + j) * 256];
        num[j][0] = v.x; num[j][1] = v.y; num[j][2] = v.z; num[j][3] = v.w;
    }
#pragma unroll
    for (int i = 0; i < 4; ++i) {
        float4 o;
        o.x = num[0][i] / acc[i][0];
        o.y = num[1][i] / acc[i][1];
        o.z = num[2][i] / acc[i][2];
        o.w = num[3][i] / acc[i][3];
        *(float4*)&out[((size_t)(b * 256 + co0 + ty * 4 + i) * 64 + h) * 64 + tx * 4] = o;
    }
}

extern "C" void kernel_launch(void* const* d_in, const int* in_sizes, int n_in,
                              void* d_out, int out_size, void* d_ws, size_t ws_size,
                              hipStream_t stream) {
    const float* x   = (const float*)d_in[0];
    const float* wq0 = (const float*)d_in[1];
    const float* wq1 = (const float*)d_in[2];
    const float* g   = (const float*)d_in[3];
    float* out = (float*)d_out;
    float* y   = (float*)d_ws;                 // 33554432 floats
    float* gt  = y + 33554432;                 // 589824 floats

    prep_gt<<<2304, 256, 0, stream>>>(g, gt);
    gabor<<<dim3(64, 32), 256, 0, stream>>>(x, wq0, wq1, y);
    dn<<<dim3(4, 64, 32), 256, 0, stream>>>(y, gt, out);
}

// Round 2
// 564.609 us; speedup vs baseline: 4.1333x; 4.1333x over previous
//
#include <hip/hip_runtime.h>
#include <cstddef>

// VOneBlock R2: dn via MFMA 16x16x32 bf16 with hi/lo split (3-term), A from L2 in
// fragment order, B staged in LDS with 17-granule row stride (conflict-free).
// ws (bytes): [0, 134217728) y2 bf16 [b][h][w][split][256ci]
//             [134217728, +2359296) gf bf16 fragment-ordered [kxy][wv][m][cc][s][lane][8]

#define NSC 128

typedef short s8v __attribute__((ext_vector_type(8)));   // 8 bf16 in 4 VGPRs
typedef float f4v __attribute__((ext_vector_type(4)));

__device__ __forceinline__ short f2bf(float f) {
    unsigned u = __float_as_uint(f);
    unsigned r = (u + 0x7fffu + ((u >> 16) & 1u)) >> 16;
    return (short)r;
}
__device__ __forceinline__ float bf2f(unsigned short s) {
    return __uint_as_float(((unsigned)s) << 16);
}

__global__ __launch_bounds__(256) void prep_g(const float* __restrict__ g,
                                              short* __restrict__ gf) {
    int t = blockIdx.x * 256 + threadIdx.x;      // 9*256*256 = 589824
    int co = t & 255, ci = (t >> 8) & 255, kxy = t >> 16;
    float v = g[((size_t)co * 256 + ci) * 9 + kxy];
    short hi = f2bf(v);
    short lo = f2bf(v - bf2f((unsigned short)hi));
    int wv = co >> 6, m = (co >> 4) & 3, i = co & 15;
    int cc = ci >> 5, q = (ci >> 3) & 3, j = ci & 7;
    int l = q * 16 + i;
    size_t base = ((((size_t)(kxy * 4 + wv) * 4 + m) * 8 + cc) * 2) * 512 + (size_t)l * 8 + j;
    gf[base] = hi;           // split 0
    gf[base + 512] = lo;     // split 1
}

__global__ __launch_bounds__(256) void gabor(const float* __restrict__ x,
                                             const float* __restrict__ wq0,
                                             const float* __restrict__ wq1,
                                             short* __restrict__ y2) {
    __shared__ float xbuf[5][132];
    int oh = blockIdx.x, b = blockIdx.y, c = threadIdx.x;
    for (int i = c; i < 5 * 132; i += 256) (&xbuf[0][0])[i] = 0.f;
    __syncthreads();
    int ihb = oh * 2 - 2;
    for (int i = c; i < 5 * 128; i += 256) {
        int r = i >> 7, col = i & 127;
        int ih = ihb + r;
        if ((unsigned)ih < 128u)
            xbuf[r][col + 2] = x[((size_t)b * 128 + ih) * 128 + col];
    }
    float w0[25], w1[25];
#pragma unroll
    for (int i = 0; i < 25; ++i) w0[i] = wq0[c * 25 + i];
#pragma unroll
    for (int i = 0; i < 25; ++i) w1[i] = wq1[c * 25 + i];
    __syncthreads();
    short* yb = y2 + ((size_t)(b * 64 + oh) * 64) * 512 + c;
    for (int ow = 0; ow < 64; ++ow) {
        float q0 = 0.f, q1 = 0.f;
        int cb = ow * 2;
#pragma unroll
        for (int ky = 0; ky < 5; ++ky)
#pragma unroll
            for (int kx = 0; kx < 5; ++kx) {
                float xv = xbuf[ky][cb + kx];
                q0 = fmaf(w0[ky * 5 + kx], xv, q0);
                q1 = fmaf(w1[ky * 5 + kx], xv, q1);
            }
        float v = (c < NSC) ? fmaxf(q0, 0.f)
                            : sqrtf(fmaf(q0, q0, q1 * q1)) * 0.70710678118654752f;
        v *= 25.f;
        short hi = f2bf(v);
        short lo = f2bf(v - bf2f((unsigned short)hi));
        yb[(size_t)ow * 512] = hi;
        yb[(size_t)ow * 512 + 256] = lo;
    }
}

// block = (h, b): 256 co x 64 w. 4 waves, each 64co x 64w = 4x4 frags of 16x16.
__global__ __launch_bounds__(256) void dn(const short* __restrict__ y2,
                                          const short* __restrict__ gf,
                                          float* __restrict__ out) {
    __shared__ short bhi[66 * 136];   // row stride 17 granules (odd mod 8 -> 2-way free)
    __shared__ short blo[66 * 136];
    int h = blockIdx.x, b = blockIdx.y;
    int tid = threadIdx.x;
    int wv = tid >> 6, l = tid & 63;
    int li = l & 15, lq = l >> 4;

    f4v acc[4][4];
#pragma unroll
    for (int m = 0; m < 4; ++m)
#pragma unroll
        for (int n = 0; n < 4; ++n)
            acc[m][n] = (f4v){0.f, 0.f, 0.f, 0.f};

    const s8v* BH = (const s8v*)bhi;
    const s8v* BL = (const s8v*)blo;
    const s8v* GA = (const s8v*)gf;

    for (int ky = 0; ky < 3; ++ky) {
        int hh = h + ky - 1;
        bool vrow = (unsigned)hh < 64u;
        for (int half = 0; half < 2; ++half) {
            __syncthreads();   // previous compute done reading LDS
            for (int t = tid; t < 66 * 16; t += 256) {
                int wl = t >> 4, gr = t & 15;
                int w = wl - 1;
                float4 vh = {0.f, 0.f, 0.f, 0.f}, vl = {0.f, 0.f, 0.f, 0.f};
                if (vrow && (unsigned)w < 64u) {
                    const float4* rowbase =
                        (const float4*)(y2 + (size_t)((b * 64 + hh) * 64) * 512);
                    vh = rowbase[(size_t)w * 64 + half * 16 + gr];
                    vl = rowbase[(size_t)w * 64 + 32 + half * 16 + gr];
                }
                *(float4*)&bhi[wl * 136 + gr * 8] = vh;
                *(float4*)&blo[wl * 136 + gr * 8] = vl;
            }
            __syncthreads();
            for (int kx = 0; kx < 3; ++kx) {
                int kxy = ky * 3 + kx;
#pragma unroll
                for (int cc = 0; cc < 4; ++cc) {
                    int ccg = half * 4 + cc;
                    s8v Bh[4], Bl[4];
#pragma unroll
                    for (int nt = 0; nt < 4; ++nt) {
                        int gidx = (nt * 16 + li + kx) * 17 + cc * 4 + lq;
                        Bh[nt] = BH[gidx];
                        Bl[nt] = BL[gidx];
                    }
#pragma unroll
                    for (int m = 0; m < 4; ++m) {
                        size_t ab = ((((size_t)(kxy * 4 + wv) * 4 + m) * 8 + ccg) * 2) * 64 + l;
                        s8v Ah = GA[ab];
                        s8v Al = GA[ab + 64];
#pragma unroll
                        for (int nt = 0; nt < 4; ++nt) {
                            acc[m][nt] = __builtin_amdgcn_mfma_f32_16x16x32_bf16(Ah, Bh[nt], acc[m][nt], 0, 0, 0);
                            acc[m][nt] = __builtin_amdgcn_mfma_f32_16x16x32_bf16(Ah, Bl[nt], acc[m][nt], 0, 0, 0);
                            acc[m][nt] = __builtin_amdgcn_mfma_f32_16x16x32_bf16(Al, Bh[nt], acc[m][nt], 0, 0, 0);
                        }
                    }
                }
            }
        }
    }

    // epilogue: out = y / under  (numerator = hi+lo from y2), write NCHW
    const short* nrow = y2 + (size_t)((b * 64 + h) * 64) * 512;
#pragma unroll
    for (int m = 0; m < 4; ++m) {
        int co = wv * 64 + m * 16 + lq * 4;
#pragma unroll
        for (int nt = 0; nt < 4; ++nt) {
            int w = nt * 16 + li;
            const short* np = nrow + (size_t)w * 512 + co;
            ushort4 nh = *(const ushort4*)np;
            ushort4 nl = *(const ushort4*)(np + 256);
            float n0 = bf2f(nh.x) + bf2f(nl.x);
            float n1 = bf2f(nh.y) + bf2f(nl.y);
            float n2 = bf2f(nh.z) + bf2f(nl.z);
            float n3 = bf2f(nh.w) + bf2f(nl.w);
            size_t ob = ((size_t)(b * 256 + co) * 64 + h) * 64 + w;
            out[ob]            = n0 / acc[m][nt][0];
            out[ob + 4096]     = n1 / acc[m][nt][1];
            out[ob + 2 * 4096] = n2 / acc[m][nt][2];
            out[ob + 3 * 4096] = n3 / acc[m][nt][3];
        }
    }
}

extern "C" void kernel_launch(void* const* d_in, const int* in_sizes, int n_in,
                              void* d_out, int out_size, void* d_ws, size_t ws_size,
                              hipStream_t stream) {
    const float* x   = (const float*)d_in[0];
    const float* wq0 = (const float*)d_in[1];
    const float* wq1 = (const float*)d_in[2];
    const float* g   = (const float*)d_in[3];
    float* out = (float*)d_out;
    short* y2 = (short*)d_ws;            // 67,108,864 bf16 = 134,217,728 B
    short* gf = y2 + 67108864;           // 1,179,648 bf16 = 2,359,296 B

    prep_g<<<2304, 256, 0, stream>>>(g, gf);
    gabor<<<dim3(64, 32), 256, 0, stream>>>(x, wq0, wq1, y2);
    dn<<<dim3(64, 32), 256, 0, stream>>>(y2, gf, out);
}